// Round 9
// baseline (1030.790 us; speedup 1.0000x reference)
//
#include <hip/hip_runtime.h>

// ---------------------------------------------------------------------------
// Problem constants (B=16, N=128, FIN=D=512)
// ---------------------------------------------------------------------------
#define BATCH 16
#define NNODE 128
#define DIM 512
#define NP1 129              // N+1 (with virtual node)
#define EDSZ (NP1 * NP1)     // 16641 per batch
#define BIGF 3.0e38f         // sentinel (finite)

// ---------------------------------------------------------------------------
// GEMM (NT): Y[m][n] = relu( sum_k A[m][k] * W[n][k] + bias[n] )
// ---------------------------------------------------------------------------
__global__ __launch_bounds__(256) void gemm_nt_relu(
    const float* __restrict__ A, const float* __restrict__ W,
    const float* __restrict__ bias, float* __restrict__ Y,
    int M, int N, int K) {
  __shared__ float sA[16][65];
  __shared__ float sB[16][65];
  const int tid = threadIdx.x;
  const int m0 = blockIdx.x * 64;
  const int n0 = blockIdx.y * 64;
  const int tm = tid / 16, tn = tid % 16;
  const int lr = tid / 4;
  const int lk = (tid % 4) * 4;
  float acc[4][4] = {};
  for (int k0 = 0; k0 < K; k0 += 16) {
    float4 av = *(const float4*)(A + (size_t)(m0 + lr) * K + k0 + lk);
    float4 wv = *(const float4*)(W + (size_t)(n0 + lr) * K + k0 + lk);
    sA[lk + 0][lr] = av.x; sA[lk + 1][lr] = av.y;
    sA[lk + 2][lr] = av.z; sA[lk + 3][lr] = av.w;
    sB[lk + 0][lr] = wv.x; sB[lk + 1][lr] = wv.y;
    sB[lk + 2][lr] = wv.z; sB[lk + 3][lr] = wv.w;
    __syncthreads();
#pragma unroll
    for (int k = 0; k < 16; ++k) {
      float a[4], b[4];
#pragma unroll
      for (int q = 0; q < 4; ++q) { a[q] = sA[k][tm * 4 + q]; b[q] = sB[k][tn * 4 + q]; }
#pragma unroll
      for (int i = 0; i < 4; ++i)
#pragma unroll
        for (int j = 0; j < 4; ++j) acc[i][j] = fmaf(a[i], b[j], acc[i][j]);
    }
    __syncthreads();
  }
#pragma unroll
  for (int i = 0; i < 4; ++i) {
    int m = m0 + tm * 4 + i;
#pragma unroll
    for (int j = 0; j < 4; ++j) {
      int n = n0 + tn * 4 + j;
      Y[(size_t)m * N + n] = fmaxf(acc[i][j] + bias[n], 0.f);
    }
  }
}

// ---------------------------------------------------------------------------
// Single-row embed (virtual node)
// ---------------------------------------------------------------------------
__global__ __launch_bounds__(256) void vec_gemm_relu(
    const float* __restrict__ x, const float* __restrict__ W,
    const float* __restrict__ bias, float* __restrict__ y) {
  __shared__ float sx[DIM];
  for (int k = threadIdx.x; k < DIM; k += 256) sx[k] = x[k];
  __syncthreads();
  for (int n = threadIdx.x; n < DIM; n += 256) {
    const float* w = W + (size_t)n * DIM;
    float s = 0.f;
    for (int k = 0; k < DIM; k += 4) {
      float4 wv = *(const float4*)(w + k);
      s = fmaf(sx[k + 0], wv.x, s);
      s = fmaf(sx[k + 1], wv.y, s);
      s = fmaf(sx[k + 2], wv.z, s);
      s = fmaf(sx[k + 3], wv.w, s);
    }
    y[n] = fmaxf(s + bias[n], 0.f);
  }
}

// ---------------------------------------------------------------------------
// cdist: d[b][i][j] = || esrow(b,i) - etrow(b,j) ||_2
// ---------------------------------------------------------------------------
__global__ __launch_bounds__(256) void cdist_kernel(
    const float* __restrict__ es, const float* __restrict__ et,
    const float* __restrict__ ev, float* __restrict__ d) {
  const int b = blockIdx.z;
  const int i0 = blockIdx.x * 32;
  const int j0 = blockIdx.y * 32;
  __shared__ float sA[32][33];
  __shared__ float sB[32][33];
  const int tid = threadIdx.x;
  const int ty = tid / 16, tx = tid % 16;
  const int lr = tid / 8;
  const int lk4 = (tid % 8) * 4;
  const int gi = i0 + lr;
  const int gj = j0 + lr;
  const float* pa = (gi < NNODE) ? (es + ((size_t)b * NNODE + gi) * DIM) : ev;
  const float* pb = (gj < NNODE) ? (et + ((size_t)b * NNODE + gj) * DIM) : ev;
  float acc[2][2] = {};
  for (int k0 = 0; k0 < DIM; k0 += 32) {
    float4 av = *(const float4*)(pa + k0 + lk4);
    float4 bv = *(const float4*)(pb + k0 + lk4);
    sA[lr][lk4 + 0] = av.x; sA[lr][lk4 + 1] = av.y;
    sA[lr][lk4 + 2] = av.z; sA[lr][lk4 + 3] = av.w;
    sB[lr][lk4 + 0] = bv.x; sB[lr][lk4 + 1] = bv.y;
    sB[lr][lk4 + 2] = bv.z; sB[lr][lk4 + 3] = bv.w;
    __syncthreads();
#pragma unroll 8
    for (int k = 0; k < 32; ++k) {
      float a0 = sA[ty * 2 + 0][k], a1 = sA[ty * 2 + 1][k];
      float b0 = sB[tx * 2 + 0][k], b1 = sB[tx * 2 + 1][k];
      float d00 = a0 - b0, d01 = a0 - b1, d10 = a1 - b0, d11 = a1 - b1;
      acc[0][0] = fmaf(d00, d00, acc[0][0]);
      acc[0][1] = fmaf(d01, d01, acc[0][1]);
      acc[1][0] = fmaf(d10, d10, acc[1][0]);
      acc[1][1] = fmaf(d11, d11, acc[1][1]);
    }
    __syncthreads();
  }
#pragma unroll
  for (int i = 0; i < 2; ++i) {
    int gi2 = i0 + ty * 2 + i;
#pragma unroll
    for (int j = 0; j < 2; ++j) {
      int gj2 = j0 + tx * 2 + j;
      if (gi2 < NP1 && gj2 < NP1)
        d[(size_t)b * EDSZ + gi2 * NP1 + gj2] = sqrtf(acc[i][j]);
    }
  }
}

// ---------------------------------------------------------------------------
// Deterministic per-batch sum (fp64 tree)
// ---------------------------------------------------------------------------
__global__ __launch_bounds__(256) void batch_sum(
    const float* __restrict__ d, float* __restrict__ sums) {
  const int b = blockIdx.x;
  double s = 0.0;
  for (int idx = threadIdx.x; idx < EDSZ; idx += 256)
    s += (double)d[(size_t)b * EDSZ + idx];
  __shared__ double red[256];
  red[threadIdx.x] = s;
  __syncthreads();
  for (int off = 128; off; off >>= 1) {
    if (threadIdx.x < off) red[threadIdx.x] += red[threadIdx.x + off];
    __syncthreads();
  }
  if (threadIdx.x == 0) sums[b] = (float)red[0];
}

// ---------------------------------------------------------------------------
// normalize: edit = d / sum[b] * N*N
// ---------------------------------------------------------------------------
__global__ __launch_bounds__(256) void normalize_kernel(
    const float* __restrict__ d, const float* __restrict__ sums,
    float* __restrict__ edit) {
  int idx = blockIdx.x * 256 + threadIdx.x;
  if (idx < BATCH * EDSZ) {
    int b = idx / EDSZ;
    edit[idx] = d[idx] / sums[b] * (float)(NNODE * NNODE);
  }
}

// ---------------------------------------------------------------------------
// cross-lane helpers: 32-bit packed argmin on the VALU pipe.
// key = (f32 bits of nonneg value, low 7 mantissa bits replaced by col).
// Unsigned order == value order (to within 2^-17 rel; ties -> lowest col).
// Exact values are recovered by readlane from the winner lane afterwards,
// so all dual arithmetic stays exact (perturbation limited to pop order,
// ~1e-6 abs — far inside the validated 8e-3 robustness margin).
// ---------------------------------------------------------------------------
__device__ __forceinline__ unsigned key_of(float m, int col) {
  return (__float_as_uint(m) & 0xFFFFFF80u) | (unsigned)col;
}

template <int CTRL>
__device__ __forceinline__ unsigned dpp_umin_step(unsigned x) {
  const unsigned o = (unsigned)__builtin_amdgcn_update_dpp(
      (int)0xFFFFFFFFu, (int)x, CTRL, 0xf, 0xf, false);
  return o < x ? o : x;
}

// wave64 min-key; valid result broadcast from lane 63.
__device__ __forceinline__ unsigned wave_umin_key(unsigned x) {
  x = dpp_umin_step<0x111>(x);  // row_shr:1
  x = dpp_umin_step<0x112>(x);  // row_shr:2
  x = dpp_umin_step<0x114>(x);  // row_shr:4
  x = dpp_umin_step<0x118>(x);  // row_shr:8
  x = dpp_umin_step<0x142>(x);  // row_bcast:15
  x = dpp_umin_step<0x143>(x);  // row_bcast:31
  return (unsigned)__builtin_amdgcn_readlane((int)x, 63);
}

// merged (min1,min2) reduction: one DPP chain carries a sorted pair.
template <int CTRL>
__device__ __forceinline__ void dpp_umin2_step(unsigned& m1, unsigned& m2) {
  const unsigned o1 = (unsigned)__builtin_amdgcn_update_dpp(
      (int)0xFFFFFFFFu, (int)m1, CTRL, 0xf, 0xf, false);
  const unsigned o2 = (unsigned)__builtin_amdgcn_update_dpp(
      (int)0xFFFFFFFFu, (int)m2, CTRL, 0xf, 0xf, false);
  const unsigned lo = m1 < o1 ? m1 : o1;
  const unsigned hi = m1 < o1 ? o1 : m1;
  const unsigned yo = m2 < o2 ? m2 : o2;
  m1 = lo;
  m2 = hi < yo ? hi : yo;
}

__device__ __forceinline__ void wave_umin2_key(unsigned a, unsigned b,
                                               unsigned& k1, unsigned& k2) {
  unsigned m1 = a < b ? a : b;
  unsigned m2 = a < b ? b : a;
  dpp_umin2_step<0x111>(m1, m2);
  dpp_umin2_step<0x112>(m1, m2);
  dpp_umin2_step<0x114>(m1, m2);
  dpp_umin2_step<0x118>(m1, m2);
  dpp_umin2_step<0x142>(m1, m2);
  dpp_umin2_step<0x143>(m1, m2);
  k1 = (unsigned)__builtin_amdgcn_readlane((int)m1, 63);
  k2 = (unsigned)__builtin_amdgcn_readlane((int)m2, 63);
}

__device__ __forceinline__ float fsel2(float a0, float a1, int s) {
  return (s == 0) ? a0 : a1;
}
__device__ __forceinline__ int isel2(int a0, int a1, int s) {
  return (s == 0) ? a0 : a1;
}
__device__ __forceinline__ float readlane_f32(float x, int lane) {
  return __uint_as_float(
      (unsigned)__builtin_amdgcn_readlane((int)__float_as_uint(x), lane));
}

// ---------------------------------------------------------------------------
// LSAPE collapsed to a dense 128x128 LSAP, solved LAPJV-style:
//   Phase 1: column reduction (v = column minima + greedy assignment)
//   Phase 1.5: augmenting row reduction, canonical 2-run list semantics
//              (displaced row reprocessed this run iff v strictly dropped,
//               else deferred to next run; capped with exact-SAP fallthrough)
//   Phase 2: exact shortest-augmenting-path for remaining free rows.
// ONE WAVE per batch, lane owns 2 columns, VALU-pipe cross-lane ops only.
// Duals stay feasible+tight at every hand-off: v only decreases; ARR rows
// get exact u = second-min; displaced rows keep their old (feasible) u.
// ---------------------------------------------------------------------------
__global__ __launch_bounds__(64) void lsap_kernel(
    const float* __restrict__ edit, float* __restrict__ Aout,
    float* __restrict__ geds) {
  const int b = blockIdx.x;
  const float* ec = edit + (size_t)b * EDSZ;
  float* A = Aout + (size_t)b * EDSZ;
  const int lane = threadIdx.x;
  const int cbase = lane * 2;  // first owned column (0-based), 2 per lane

  __shared__ float D[NNODE * NNODE];  // 64 KB dense collapsed cost

  // stage D = min(sub, del+ins); coalesced global reads (L2-resident)
  for (int idx = lane; idx < NNODE * NNODE; idx += 64) {
    const int i = idx >> 7, j = idx & 127;
    const float sub = ec[i * NP1 + j];
    const float di = ec[i * NP1 + NNODE] + ec[NNODE * NP1 + j];
    D[idx] = fminf(sub, di);
  }
  for (int idx = lane; idx < EDSZ; idx += 64) A[idx] = 0.f;
  __syncthreads();

  // per-lane state: 2 columns (v, minv, way, p) + 2 rows (u)
  float u0 = 0.f, u1 = 0.f;
  float v0 = 0.f, v1 = 0.f;
  float m0, m1;
  int w0 = 0, w1 = 0;
  int p0 = 0, p1 = 0;

  // ---------------- Phase 1: column reduction on dense D ----------------
  int y0 = 0, y1 = 0;
  {
    float c0 = BIGF, c1 = BIGF;
    for (int r = 0; r < NNODE; ++r) {
      const float2 f = *(const float2*)&D[r * NNODE + cbase];
      if (f.x < c0) { c0 = f.x; y0 = r; }
      if (f.y < c1) { c1 = f.y; y1 = r; }
    }
    v0 = c0; v1 = c1;
  }

  // Greedy conflict-free assignment (wave-uniform scalar walk over columns).
  unsigned long long ra0 = 0, ra1 = 0;  // assigned-row bits (0..63, 64..127)
  for (int j = 0; j < NNODE; ++j) {
    const int jl = j >> 1, jq = j & 1;
    const int i1 = __builtin_amdgcn_readlane(isel2(y0, y1, jq), jl);
    const int bit = i1 & 63;
    const unsigned long long msk = (i1 < 64) ? ra0 : ra1;
    if (!((msk >> bit) & 1ull)) {
      if (i1 < 64) ra0 |= 1ull << bit; else ra1 |= 1ull << bit;
      if (lane == jl) {
        if (jq == 0) p0 = i1 + 1;
        else p1 = i1 + 1;
      }
    }
  }

  // ---------------- Phase 1.5: augmenting row reduction (2 runs) ----------
  {
    unsigned long long cur0 = ~ra0, cur1 = ~ra1;
    int steps = 0;
    for (int run = 0; run < 2; ++run) {
      unsigned long long nxt0 = 0, nxt1 = 0;
      while ((cur0 | cur1) != 0 && steps < 640) {
        ++steps;
        int i;
        if (cur0) { i = __builtin_ctzll(cur0); cur0 &= cur0 - 1; }
        else { i = 64 + __builtin_ctzll(cur1); cur1 &= cur1 - 1; }

        const float2 f = *(const float2*)&D[i * NNODE + cbase];
        const float r0 = fmaxf(f.x - v0, 0.f);
        const float r1 = fmaxf(f.y - v1, 0.f);
        unsigned k1, k2;
        wave_umin2_key(key_of(r0, cbase + 0), key_of(r1, cbase + 1), k1, k2);
        const int j1 = (int)(k1 & 127u), j2 = (int)(k2 & 127u);
        const float u1v = readlane_f32(fsel2(r0, r1, j1 & 1), j1 >> 1);
        const float u2v = readlane_f32(fsel2(r0, r1, j2 & 1), j2 >> 1);

        int jt = j1;
        int i1 = __builtin_amdgcn_readlane(isel2(p0, p1, j1 & 1), j1 >> 1);
        const bool lowered = (u1v < u2v);
        if (lowered) {
          const float dv = u2v - u1v;
          if (lane == (j1 >> 1)) {
            if ((j1 & 1) == 0) v0 -= dv; else v1 -= dv;
          }
        } else if (i1 != 0) {
          jt = j2;
          i1 = __builtin_amdgcn_readlane(isel2(p0, p1, j2 & 1), j2 >> 1);
        }
        // assign i -> jt with exact u[i] = u2v (feasible + tight)
        if (lane == (jt >> 1)) {
          if ((jt & 1) == 0) p0 = i + 1; else p1 = i + 1;
        }
        if (lane == (i >> 1)) {
          if ((i & 1) == 0) u0 = u2v; else u1 = u2v;
        }
        if (i < 64) ra0 |= 1ull << i; else ra1 |= 1ull << (i - 64);
        if (i1 != 0) {
          const int rr = i1 - 1;
          if (rr < 64) ra0 &= ~(1ull << rr); else ra1 &= ~(1ull << (rr - 64));
          if (lowered) {  // strict dual progress: reprocess in this run
            if (rr < 64) cur0 |= 1ull << rr; else cur1 |= 1ull << (rr - 64);
          } else {        // defer to next run
            if (rr < 64) nxt0 |= 1ull << rr; else nxt1 |= 1ull << (rr - 64);
          }
          // displaced row keeps its old u (still feasible: v only decreases)
        }
      }
      nxt0 |= cur0; nxt1 |= cur1;  // budget hit: roll over (SAP handles rest)
      cur0 = nxt0; cur1 = nxt1;
    }
  }

  // ---------------- Phase 2: SAP for each remaining free row ----------------
  for (int ii = 0; ii < NNODE; ++ii) {
    const unsigned long long amsk = (ii < 64) ? ra0 : ra1;
    if ((amsk >> (ii & 63)) & 1ull) continue;  // assigned in phase 1/1.5
    const int i = ii + 1;

    unsigned cused = 0, rused = 0;
    m0 = m1 = BIGF;
    int j0 = 0;       // current column (0 = dummy start)
    int i0 = i;       // p[0] = i
    for (int guard = 0; guard <= NNODE; ++guard) {
      // --- mark used: column j0 (skip dummy col 0) and its row i0 ---
      if (j0 > 0 && lane == ((j0 - 1) >> 1)) {
        if (((j0 - 1) & 1) == 0) { cused |= 1u; m0 = BIGF; }
        else { cused |= 2u; m1 = BIGF; }
      }
      if (lane == ((i0 - 1) >> 1)) rused |= 1u << ((i0 - 1) & 1);

      // --- broadcast u[i0] from owning lane (i0 uniform -> readlane) ---
      const float u_i0 = readlane_f32(fsel2(u0, u1, (i0 - 1) & 1), (i0 - 1) >> 1);

      // --- dense cost row: one float2 per lane ---
      const float2 f = *(const float2*)&D[(i0 - 1) * NNODE + cbase];

      // --- relax free columns; clamp >=0 keeps key ordering sound ---
      const bool f0 = !(cused & 1u), f1 = !(cused & 2u);
      {
        float cur = fmaxf(f.x - u_i0 - v0, 0.f);
        bool up = f0 && (cur < m0);
        m0 = up ? cur : m0; w0 = up ? j0 : w0;
      }
      {
        float cur = fmaxf(f.y - u_i0 - v1, 0.f);
        bool up = f1 && (cur < m1);
        m1 = up ? cur : m1; w1 = up ? j0 : w1;
      }

      // --- 32-bit key argmin; exact delta via winner readlane ---
      const unsigned ka = key_of(m0, cbase + 0);
      const unsigned kb = key_of(m1, cbase + 1);
      const unsigned kmin = wave_umin_key(ka < kb ? ka : kb);
      const int jcol = (int)(kmin & 127u);
      const float delta = readlane_f32(fsel2(m0, m1, jcol & 1), jcol >> 1);
      const int j1 = jcol + 1;

      // --- dual updates (registers only) ---
      if (!f0) v0 -= delta; else m0 = fmaxf(m0 - delta, 0.f);
      if (!f1) v1 -= delta; else m1 = fmaxf(m1 - delta, 0.f);
      if (rused & 1u) u0 += delta;
      if (rused & 2u) u1 += delta;

      // --- next (or break on free column) ---
      const int pj1 = __builtin_amdgcn_readlane(
          isel2(p0, p1, (j1 - 1) & 1), (j1 - 1) >> 1);
      j0 = j1;
      if (pj1 == 0) break;
      i0 = pj1;
    }

    // --- augment along way[] chain (uniform walk via readlane) ---
    int jc = j0;
    while (jc != 0) {
      const int cl = (jc - 1) >> 1, cq = (jc - 1) & 1;
      const int jp = __builtin_amdgcn_readlane(isel2(w0, w1, cq), cl);
      const int js = (jp == 0) ? 1 : jp;  // safe index for speculative readlane
      const int pvr = __builtin_amdgcn_readlane(
          isel2(p0, p1, (js - 1) & 1), (js - 1) >> 1);
      const int pv = (jp == 0) ? i : pvr;
      if (lane == cl) {
        if (cq == 0) p0 = pv;
        else p1 = pv;
      }
      jc = jp;
    }
  }

  // --- emit A and geds: column j assigned row p[j+1]-1; re-split branches ---
  double contrib = 0.0;
  {
    const int pr[2] = {p0, p1};
#pragma unroll
    for (int q = 0; q < 2; ++q) {
      const int j = cbase + q;
      const int i = pr[q] - 1;
      const float sub = ec[i * NP1 + j];
      const float di = ec[i * NP1 + NNODE] + ec[NNODE * NP1 + j];
      if (sub < di) {
        A[i * NP1 + j] = 1.f;
        contrib += (double)sub;
      } else {
        A[i * NP1 + NNODE] = 1.f;    // delete row i
        A[NNODE * NP1 + j] = 1.f;    // insert col j
        contrib += (double)di;
      }
    }
  }
#pragma unroll
  for (int off = 32; off; off >>= 1) contrib += __shfl_xor(contrib, off);
  if (lane == 0) geds[b] = (float)(contrib / 256.0);
}

// ---------------------------------------------------------------------------
// launch
// ---------------------------------------------------------------------------
extern "C" void kernel_launch(void* const* d_in, const int* in_sizes, int n_in,
                              void* d_out, int out_size, void* d_ws, size_t ws_size,
                              hipStream_t stream) {
  const float* x_s  = (const float*)d_in[0];
  const float* x_t  = (const float*)d_in[1];
  const float* W1   = (const float*)d_in[2];
  const float* b1   = (const float*)d_in[3];
  const float* W2   = (const float*)d_in[4];
  const float* b2   = (const float*)d_in[5];
  const float* virt = (const float*)d_in[6];

  const int M = BATCH * NNODE;  // 2048

  float* ws    = (float*)d_ws;
  float* h_s   = ws;
  float* h_t   = h_s + (size_t)M * DIM;
  float* e_s   = h_t + (size_t)M * DIM;
  float* e_t   = e_s + (size_t)M * DIM;
  float* h_v   = e_t + (size_t)M * DIM;
  float* e_v   = h_v + DIM;
  float* d_raw = e_v + DIM;
  float* sums  = d_raw + (size_t)BATCH * EDSZ;

  float* Aout = (float*)d_out;
  float* edit = Aout + (size_t)BATCH * EDSZ;
  float* geds = edit + (size_t)BATCH * EDSZ;

  dim3 gblk(M / 64, DIM / 64);
  gemm_nt_relu<<<gblk, 256, 0, stream>>>(x_s, W1, b1, h_s, M, DIM, DIM);
  gemm_nt_relu<<<gblk, 256, 0, stream>>>(x_t, W1, b1, h_t, M, DIM, DIM);
  vec_gemm_relu<<<1, 256, 0, stream>>>(virt, W1, b1, h_v);
  gemm_nt_relu<<<gblk, 256, 0, stream>>>(h_s, W2, b2, e_s, M, DIM, DIM);
  gemm_nt_relu<<<gblk, 256, 0, stream>>>(h_t, W2, b2, e_t, M, DIM, DIM);
  vec_gemm_relu<<<1, 256, 0, stream>>>(h_v, W2, b2, e_v);

  cdist_kernel<<<dim3(5, 5, BATCH), 256, 0, stream>>>(e_s, e_t, e_v, d_raw);
  batch_sum<<<BATCH, 256, 0, stream>>>(d_raw, sums);
  normalize_kernel<<<(BATCH * EDSZ + 255) / 256, 256, 0, stream>>>(d_raw, sums, edit);
  lsap_kernel<<<BATCH, 64, 0, stream>>>(edit, Aout, geds);
}

// Round 10
// 903.288 us; speedup vs baseline: 1.1412x; 1.1412x over previous
//
#include <hip/hip_runtime.h>

// ---------------------------------------------------------------------------
// Problem constants (B=16, N=128, FIN=D=512)
// ---------------------------------------------------------------------------
#define BATCH 16
#define NNODE 128
#define DIM 512
#define NP1 129              // N+1 (with virtual node)
#define EDSZ (NP1 * NP1)     // 16641 per batch
#define BIGF 3.0e38f         // sentinel (finite)

// ---------------------------------------------------------------------------
// GEMM (NT): Y[m][n] = relu( sum_k A[m][k] * W[n][k] + bias[n] )
// ---------------------------------------------------------------------------
__global__ __launch_bounds__(256) void gemm_nt_relu(
    const float* __restrict__ A, const float* __restrict__ W,
    const float* __restrict__ bias, float* __restrict__ Y,
    int M, int N, int K) {
  __shared__ float sA[16][65];
  __shared__ float sB[16][65];
  const int tid = threadIdx.x;
  const int m0 = blockIdx.x * 64;
  const int n0 = blockIdx.y * 64;
  const int tm = tid / 16, tn = tid % 16;
  const int lr = tid / 4;
  const int lk = (tid % 4) * 4;
  float acc[4][4] = {};
  for (int k0 = 0; k0 < K; k0 += 16) {
    float4 av = *(const float4*)(A + (size_t)(m0 + lr) * K + k0 + lk);
    float4 wv = *(const float4*)(W + (size_t)(n0 + lr) * K + k0 + lk);
    sA[lk + 0][lr] = av.x; sA[lk + 1][lr] = av.y;
    sA[lk + 2][lr] = av.z; sA[lk + 3][lr] = av.w;
    sB[lk + 0][lr] = wv.x; sB[lk + 1][lr] = wv.y;
    sB[lk + 2][lr] = wv.z; sB[lk + 3][lr] = wv.w;
    __syncthreads();
#pragma unroll
    for (int k = 0; k < 16; ++k) {
      float a[4], b[4];
#pragma unroll
      for (int q = 0; q < 4; ++q) { a[q] = sA[k][tm * 4 + q]; b[q] = sB[k][tn * 4 + q]; }
#pragma unroll
      for (int i = 0; i < 4; ++i)
#pragma unroll
        for (int j = 0; j < 4; ++j) acc[i][j] = fmaf(a[i], b[j], acc[i][j]);
    }
    __syncthreads();
  }
#pragma unroll
  for (int i = 0; i < 4; ++i) {
    int m = m0 + tm * 4 + i;
#pragma unroll
    for (int j = 0; j < 4; ++j) {
      int n = n0 + tn * 4 + j;
      Y[(size_t)m * N + n] = fmaxf(acc[i][j] + bias[n], 0.f);
    }
  }
}

// ---------------------------------------------------------------------------
// Single-row embed (virtual node)
// ---------------------------------------------------------------------------
__global__ __launch_bounds__(256) void vec_gemm_relu(
    const float* __restrict__ x, const float* __restrict__ W,
    const float* __restrict__ bias, float* __restrict__ y) {
  __shared__ float sx[DIM];
  for (int k = threadIdx.x; k < DIM; k += 256) sx[k] = x[k];
  __syncthreads();
  for (int n = threadIdx.x; n < DIM; n += 256) {
    const float* w = W + (size_t)n * DIM;
    float s = 0.f;
    for (int k = 0; k < DIM; k += 4) {
      float4 wv = *(const float4*)(w + k);
      s = fmaf(sx[k + 0], wv.x, s);
      s = fmaf(sx[k + 1], wv.y, s);
      s = fmaf(sx[k + 2], wv.z, s);
      s = fmaf(sx[k + 3], wv.w, s);
    }
    y[n] = fmaxf(s + bias[n], 0.f);
  }
}

// ---------------------------------------------------------------------------
// cdist: d[b][i][j] = || esrow(b,i) - etrow(b,j) ||_2
// ---------------------------------------------------------------------------
__global__ __launch_bounds__(256) void cdist_kernel(
    const float* __restrict__ es, const float* __restrict__ et,
    const float* __restrict__ ev, float* __restrict__ d) {
  const int b = blockIdx.z;
  const int i0 = blockIdx.x * 32;
  const int j0 = blockIdx.y * 32;
  __shared__ float sA[32][33];
  __shared__ float sB[32][33];
  const int tid = threadIdx.x;
  const int ty = tid / 16, tx = tid % 16;
  const int lr = tid / 8;
  const int lk4 = (tid % 8) * 4;
  const int gi = i0 + lr;
  const int gj = j0 + lr;
  const float* pa = (gi < NNODE) ? (es + ((size_t)b * NNODE + gi) * DIM) : ev;
  const float* pb = (gj < NNODE) ? (et + ((size_t)b * NNODE + gj) * DIM) : ev;
  float acc[2][2] = {};
  for (int k0 = 0; k0 < DIM; k0 += 32) {
    float4 av = *(const float4*)(pa + k0 + lk4);
    float4 bv = *(const float4*)(pb + k0 + lk4);
    sA[lr][lk4 + 0] = av.x; sA[lr][lk4 + 1] = av.y;
    sA[lr][lk4 + 2] = av.z; sA[lr][lk4 + 3] = av.w;
    sB[lr][lk4 + 0] = bv.x; sB[lr][lk4 + 1] = bv.y;
    sB[lr][lk4 + 2] = bv.z; sB[lr][lk4 + 3] = bv.w;
    __syncthreads();
#pragma unroll 8
    for (int k = 0; k < 32; ++k) {
      float a0 = sA[ty * 2 + 0][k], a1 = sA[ty * 2 + 1][k];
      float b0 = sB[tx * 2 + 0][k], b1 = sB[tx * 2 + 1][k];
      float d00 = a0 - b0, d01 = a0 - b1, d10 = a1 - b0, d11 = a1 - b1;
      acc[0][0] = fmaf(d00, d00, acc[0][0]);
      acc[0][1] = fmaf(d01, d01, acc[0][1]);
      acc[1][0] = fmaf(d10, d10, acc[1][0]);
      acc[1][1] = fmaf(d11, d11, acc[1][1]);
    }
    __syncthreads();
  }
#pragma unroll
  for (int i = 0; i < 2; ++i) {
    int gi2 = i0 + ty * 2 + i;
#pragma unroll
    for (int j = 0; j < 2; ++j) {
      int gj2 = j0 + tx * 2 + j;
      if (gi2 < NP1 && gj2 < NP1)
        d[(size_t)b * EDSZ + gi2 * NP1 + gj2] = sqrtf(acc[i][j]);
    }
  }
}

// ---------------------------------------------------------------------------
// Deterministic per-batch sum (fp64 tree)
// ---------------------------------------------------------------------------
__global__ __launch_bounds__(256) void batch_sum(
    const float* __restrict__ d, float* __restrict__ sums) {
  const int b = blockIdx.x;
  double s = 0.0;
  for (int idx = threadIdx.x; idx < EDSZ; idx += 256)
    s += (double)d[(size_t)b * EDSZ + idx];
  __shared__ double red[256];
  red[threadIdx.x] = s;
  __syncthreads();
  for (int off = 128; off; off >>= 1) {
    if (threadIdx.x < off) red[threadIdx.x] += red[threadIdx.x + off];
    __syncthreads();
  }
  if (threadIdx.x == 0) sums[b] = (float)red[0];
}

// ---------------------------------------------------------------------------
// normalize: edit = d / sum[b] * N*N
// ---------------------------------------------------------------------------
__global__ __launch_bounds__(256) void normalize_kernel(
    const float* __restrict__ d, const float* __restrict__ sums,
    float* __restrict__ edit) {
  int idx = blockIdx.x * 256 + threadIdx.x;
  if (idx < BATCH * EDSZ) {
    int b = idx / EDSZ;
    edit[idx] = d[idx] / sums[b] * (float)(NNODE * NNODE);
  }
}

// ---------------------------------------------------------------------------
// cross-lane helpers: 32-bit packed argmin on the VALU pipe.
// key = (f32 bits of nonneg value with low 7 mantissa bits replaced by col).
// Unsigned order == value order (to within 2^-17 rel; ties -> lowest col).
// Exact values recovered by readlane from the winner lane, so dual
// arithmetic stays exact (perturbation limited to pop order, ~1e-6 abs —
// far inside the validated 8e-3 robustness margin).
// ---------------------------------------------------------------------------
__device__ __forceinline__ unsigned key_of(float m, int col) {
  return (__float_as_uint(m) & 0xFFFFFF80u) | (unsigned)col;
}

template <int CTRL>
__device__ __forceinline__ unsigned dpp_umin_step(unsigned x) {
  const unsigned o = (unsigned)__builtin_amdgcn_update_dpp(
      (int)0xFFFFFFFFu, (int)x, CTRL, 0xf, 0xf, false);
  return o < x ? o : x;
}

// wave64 min-key; result broadcast (readlane 63).
__device__ __forceinline__ unsigned wave_umin_key(unsigned x) {
  x = dpp_umin_step<0x111>(x);  // row_shr:1
  x = dpp_umin_step<0x112>(x);  // row_shr:2
  x = dpp_umin_step<0x114>(x);  // row_shr:4
  x = dpp_umin_step<0x118>(x);  // row_shr:8
  x = dpp_umin_step<0x142>(x);  // row_bcast:15
  x = dpp_umin_step<0x143>(x);  // row_bcast:31
  return (unsigned)__builtin_amdgcn_readlane((int)x, 63);
}

// merged (min1,min2) reduction: one DPP chain carries a sorted pair.
template <int CTRL>
__device__ __forceinline__ void dpp_umin2_step(unsigned& m1, unsigned& m2) {
  const unsigned o1 = (unsigned)__builtin_amdgcn_update_dpp(
      (int)0xFFFFFFFFu, (int)m1, CTRL, 0xf, 0xf, false);
  const unsigned o2 = (unsigned)__builtin_amdgcn_update_dpp(
      (int)0xFFFFFFFFu, (int)m2, CTRL, 0xf, 0xf, false);
  const unsigned lo = m1 < o1 ? m1 : o1;
  const unsigned hi = m1 < o1 ? o1 : m1;
  const unsigned yo = m2 < o2 ? m2 : o2;
  m1 = lo;
  m2 = hi < yo ? hi : yo;
}

__device__ __forceinline__ void wave_umin2_key(unsigned a, unsigned b,
                                               unsigned& k1, unsigned& k2) {
  unsigned m1 = a < b ? a : b;
  unsigned m2 = a < b ? b : a;
  dpp_umin2_step<0x111>(m1, m2);
  dpp_umin2_step<0x112>(m1, m2);
  dpp_umin2_step<0x114>(m1, m2);
  dpp_umin2_step<0x118>(m1, m2);
  dpp_umin2_step<0x142>(m1, m2);
  dpp_umin2_step<0x143>(m1, m2);
  k1 = (unsigned)__builtin_amdgcn_readlane((int)m1, 63);
  k2 = (unsigned)__builtin_amdgcn_readlane((int)m2, 63);
}

__device__ __forceinline__ float fsel2(float a0, float a1, int s) {
  return (s == 0) ? a0 : a1;
}
__device__ __forceinline__ int isel2(int a0, int a1, int s) {
  return (s == 0) ? a0 : a1;
}
__device__ __forceinline__ float readlane_f32(float x, int lane) {
  return __uint_as_float(
      (unsigned)__builtin_amdgcn_readlane((int)__float_as_uint(x), lane));
}

// ---------------------------------------------------------------------------
// LSAPE collapsed to a dense 128x128 LSAP, full LAPJV pipeline:
//   Phase 1 : column reduction (v = column minima + greedy assignment)
//   Phase 1r: reduction transfer (assigned rows: u[i] = 2nd-best reduced
//             cost over j!=j1, v[j1] -= u[i]) — shortens later paths
//   Phase 1.5: budget-capped augmenting row reduction (R8 semantics)
//   Phase 2 : exact shortest-augmenting-path for remaining free rows
// ONE WAVE per batch, lane owns 2 columns, VALU-pipe cross-lane ops only.
// Duals stay feasible at every hand-off: v only decreases; slack at each
// assigned pair is tight by construction.
// ---------------------------------------------------------------------------
__global__ __launch_bounds__(64) void lsap_kernel(
    const float* __restrict__ edit, float* __restrict__ Aout,
    float* __restrict__ geds) {
  const int b = blockIdx.x;
  const float* ec = edit + (size_t)b * EDSZ;
  float* A = Aout + (size_t)b * EDSZ;
  const int lane = threadIdx.x;
  const int cbase = lane * 2;  // first owned column (0-based), 2 per lane

  __shared__ float D[NNODE * NNODE];  // 64 KB dense collapsed cost

  // stage D = min(sub, del+ins); coalesced global reads (L2-resident)
  for (int idx = lane; idx < NNODE * NNODE; idx += 64) {
    const int i = idx >> 7, j = idx & 127;
    const float sub = ec[i * NP1 + j];
    const float di = ec[i * NP1 + NNODE] + ec[NNODE * NP1 + j];
    D[idx] = fminf(sub, di);
  }
  for (int idx = lane; idx < EDSZ; idx += 64) A[idx] = 0.f;
  __syncthreads();

  // per-lane state: 2 columns (v, minv, way, p) + 2 rows (u, x=row->col+1)
  float u0 = 0.f, u1 = 0.f;
  float v0 = 0.f, v1 = 0.f;
  float m0, m1;
  int w0 = 0, w1 = 0;
  int p0 = 0, p1 = 0;
  int x0 = 0, x1 = 0;

  // ---------------- Phase 1: column reduction on dense D ----------------
  int y0 = 0, y1 = 0;
  {
    float c0 = BIGF, c1 = BIGF;
    for (int r = 0; r < NNODE; ++r) {
      const float2 f = *(const float2*)&D[r * NNODE + cbase];
      if (f.x < c0) { c0 = f.x; y0 = r; }
      if (f.y < c1) { c1 = f.y; y1 = r; }
    }
    v0 = c0; v1 = c1;
  }

  // Greedy conflict-free assignment (wave-uniform scalar walk over columns).
  unsigned long long ra0 = 0, ra1 = 0;  // assigned-row bits (0..63, 64..127)
  for (int j = 0; j < NNODE; ++j) {
    const int jl = j >> 1, jq = j & 1;
    const int i1 = __builtin_amdgcn_readlane(isel2(y0, y1, jq), jl);
    const int bit = i1 & 63;
    const unsigned long long msk = (i1 < 64) ? ra0 : ra1;
    if (!((msk >> bit) & 1ull)) {
      if (i1 < 64) ra0 |= 1ull << bit; else ra1 |= 1ull << bit;
      if (lane == jl) {
        if (jq == 0) p0 = i1 + 1;
        else p1 = i1 + 1;
      }
      if (lane == (i1 >> 1)) {
        if ((i1 & 1) == 0) x0 = j + 1;
        else x1 = j + 1;
      }
    }
  }

  // ---------------- Phase 1r: reduction transfer ----------------
  // For each assigned row i (col j1): u[i] = min_{j!=j1}(D[i][j]-v[j]);
  // v[j1] -= u[i]. Feasible: slack at j1 becomes exactly u[i]; others >= u[i].
  for (int ii = 0; ii < NNODE; ++ii) {
    const int xj = __builtin_amdgcn_readlane(isel2(x0, x1, ii & 1), ii >> 1);
    if (xj == 0) continue;
    const int j1 = xj - 1;
    const float2 f = *(const float2*)&D[ii * NNODE + cbase];
    float r0 = fmaxf(f.x - v0, 0.f);
    float r1 = fmaxf(f.y - v1, 0.f);
    if (cbase + 0 == j1) r0 = BIGF;
    if (cbase + 1 == j1) r1 = BIGF;
    const unsigned ka = key_of(r0, cbase + 0);
    const unsigned kb = key_of(r1, cbase + 1);
    const unsigned kmin = wave_umin_key(ka < kb ? ka : kb);
    const int jm = (int)(kmin & 127u);
    const float umin = readlane_f32(fsel2(r0, r1, jm & 1), jm >> 1);
    if (lane == (j1 >> 1)) {
      if ((j1 & 1) == 0) v0 -= umin; else v1 -= umin;
    }
    if (lane == (ii >> 1)) {
      if ((ii & 1) == 0) u0 = umin; else u1 = umin;
    }
  }

  // ---------------- Phase 1.5: augmenting row reduction (R8 semantics) ----
  {
    const int nfree0 =
        NNODE - __builtin_popcountll(ra0) - __builtin_popcountll(ra1);
    const int budget = 2 * nfree0 + 8;
    for (int step = 0; step < budget; ++step) {
      const unsigned long long fm0 = ~ra0, fm1 = ~ra1;
      int i;
      if (fm0) i = __builtin_ctzll(fm0);
      else if (fm1) i = 64 + __builtin_ctzll(fm1);
      else break;

      const float2 f = *(const float2*)&D[i * NNODE + cbase];
      const float r0 = fmaxf(f.x - v0, 0.f);
      const float r1 = fmaxf(f.y - v1, 0.f);
      unsigned k1, k2;
      wave_umin2_key(key_of(r0, cbase + 0), key_of(r1, cbase + 1), k1, k2);
      const int j1 = (int)(k1 & 127u), j2 = (int)(k2 & 127u);
      const float u1v = readlane_f32(fsel2(r0, r1, j1 & 1), j1 >> 1);
      const float u2v = readlane_f32(fsel2(r0, r1, j2 & 1), j2 >> 1);

      int jt = j1;
      int i1 = __builtin_amdgcn_readlane(isel2(p0, p1, j1 & 1), j1 >> 1);
      if (u1v < u2v) {
        const float dv = u2v - u1v;
        if (lane == (j1 >> 1)) {
          if ((j1 & 1) == 0) v0 -= dv; else v1 -= dv;
        }
      } else if (i1 != 0) {
        jt = j2;
        i1 = __builtin_amdgcn_readlane(isel2(p0, p1, j2 & 1), j2 >> 1);
      }
      // assign i -> jt with exact u[i] = u2v (feasible + tight)
      if (lane == (jt >> 1)) {
        if ((jt & 1) == 0) p0 = i + 1; else p1 = i + 1;
      }
      if (lane == (i >> 1)) {
        if ((i & 1) == 0) u0 = u2v; else u1 = u2v;
      }
      if (i < 64) ra0 |= 1ull << i; else ra1 |= 1ull << (i - 64);
      if (i1 != 0) {
        const int rr = i1 - 1;
        if (rr < 64) ra0 &= ~(1ull << rr); else ra1 &= ~(1ull << (rr - 64));
        if (lane == (rr >> 1)) {  // freed row: reset dual (always feasible)
          if ((rr & 1) == 0) u0 = 0.f; else u1 = 0.f;
        }
      }
    }
  }

  // ---------------- Phase 2: SAP for each remaining free row ----------------
  for (int ii = 0; ii < NNODE; ++ii) {
    const unsigned long long amsk = (ii < 64) ? ra0 : ra1;
    if ((amsk >> (ii & 63)) & 1ull) continue;  // assigned in phase 1/1.5
    const int i = ii + 1;

    unsigned cused = 0, rused = 0;
    m0 = m1 = BIGF;
    int j0 = 0;       // current column (0 = dummy start)
    int i0 = i;       // p[0] = i
    for (int guard = 0; guard <= NNODE; ++guard) {
      // --- mark used: column j0 (skip dummy col 0) and its row i0 ---
      if (j0 > 0 && lane == ((j0 - 1) >> 1)) {
        if (((j0 - 1) & 1) == 0) { cused |= 1u; m0 = BIGF; }
        else { cused |= 2u; m1 = BIGF; }
      }
      if (lane == ((i0 - 1) >> 1)) rused |= 1u << ((i0 - 1) & 1);

      // --- broadcast u[i0] from owning lane (i0 uniform -> readlane) ---
      const float u_i0 = readlane_f32(fsel2(u0, u1, (i0 - 1) & 1), (i0 - 1) >> 1);

      // --- dense cost row: one float2 per lane ---
      const float2 f = *(const float2*)&D[(i0 - 1) * NNODE + cbase];

      // --- relax free columns; clamp >=0 keeps key ordering sound ---
      const bool f0 = !(cused & 1u), f1 = !(cused & 2u);
      {
        float cur = fmaxf(f.x - u_i0 - v0, 0.f);
        bool up = f0 && (cur < m0);
        m0 = up ? cur : m0; w0 = up ? j0 : w0;
      }
      {
        float cur = fmaxf(f.y - u_i0 - v1, 0.f);
        bool up = f1 && (cur < m1);
        m1 = up ? cur : m1; w1 = up ? j0 : w1;
      }

      // --- 32-bit key argmin; exact delta via winner readlane ---
      const unsigned ka = key_of(m0, cbase + 0);
      const unsigned kb = key_of(m1, cbase + 1);
      const unsigned kmin = wave_umin_key(ka < kb ? ka : kb);
      const int jcol = (int)(kmin & 127u);
      const float delta = readlane_f32(fsel2(m0, m1, jcol & 1), jcol >> 1);
      const int j1 = jcol + 1;

      // --- dual updates (registers only) ---
      if (!f0) v0 -= delta; else m0 = fmaxf(m0 - delta, 0.f);
      if (!f1) v1 -= delta; else m1 = fmaxf(m1 - delta, 0.f);
      if (rused & 1u) u0 += delta;
      if (rused & 2u) u1 += delta;

      // --- next (or break on free column) ---
      const int pj1 = __builtin_amdgcn_readlane(
          isel2(p0, p1, (j1 - 1) & 1), (j1 - 1) >> 1);
      j0 = j1;
      if (pj1 == 0) break;
      i0 = pj1;
    }

    // --- augment along way[] chain (uniform walk via readlane) ---
    int jc = j0;
    while (jc != 0) {
      const int cl = (jc - 1) >> 1, cq = (jc - 1) & 1;
      const int jp = __builtin_amdgcn_readlane(isel2(w0, w1, cq), cl);
      const int js = (jp == 0) ? 1 : jp;  // safe index for speculative readlane
      const int pvr = __builtin_amdgcn_readlane(
          isel2(p0, p1, (js - 1) & 1), (js - 1) >> 1);
      const int pv = (jp == 0) ? i : pvr;
      if (lane == cl) {
        if (cq == 0) p0 = pv;
        else p1 = pv;
      }
      jc = jp;
    }
  }

  // --- emit A and geds: column j assigned row p[j+1]-1; re-split branches ---
  double contrib = 0.0;
  {
    const int pr[2] = {p0, p1};
#pragma unroll
    for (int q = 0; q < 2; ++q) {
      const int j = cbase + q;
      const int i = pr[q] - 1;
      const float sub = ec[i * NP1 + j];
      const float di = ec[i * NP1 + NNODE] + ec[NNODE * NP1 + j];
      if (sub < di) {
        A[i * NP1 + j] = 1.f;
        contrib += (double)sub;
      } else {
        A[i * NP1 + NNODE] = 1.f;    // delete row i
        A[NNODE * NP1 + j] = 1.f;    // insert col j
        contrib += (double)di;
      }
    }
  }
#pragma unroll
  for (int off = 32; off; off >>= 1) contrib += __shfl_xor(contrib, off);
  if (lane == 0) geds[b] = (float)(contrib / 256.0);
}

// ---------------------------------------------------------------------------
// launch
// ---------------------------------------------------------------------------
extern "C" void kernel_launch(void* const* d_in, const int* in_sizes, int n_in,
                              void* d_out, int out_size, void* d_ws, size_t ws_size,
                              hipStream_t stream) {
  const float* x_s  = (const float*)d_in[0];
  const float* x_t  = (const float*)d_in[1];
  const float* W1   = (const float*)d_in[2];
  const float* b1   = (const float*)d_in[3];
  const float* W2   = (const float*)d_in[4];
  const float* b2   = (const float*)d_in[5];
  const float* virt = (const float*)d_in[6];

  const int M = BATCH * NNODE;  // 2048

  float* ws    = (float*)d_ws;
  float* h_s   = ws;
  float* h_t   = h_s + (size_t)M * DIM;
  float* e_s   = h_t + (size_t)M * DIM;
  float* e_t   = e_s + (size_t)M * DIM;
  float* h_v   = e_t + (size_t)M * DIM;
  float* e_v   = h_v + DIM;
  float* d_raw = e_v + DIM;
  float* sums  = d_raw + (size_t)BATCH * EDSZ;

  float* Aout = (float*)d_out;
  float* edit = Aout + (size_t)BATCH * EDSZ;
  float* geds = edit + (size_t)BATCH * EDSZ;

  dim3 gblk(M / 64, DIM / 64);
  gemm_nt_relu<<<gblk, 256, 0, stream>>>(x_s, W1, b1, h_s, M, DIM, DIM);
  gemm_nt_relu<<<gblk, 256, 0, stream>>>(x_t, W1, b1, h_t, M, DIM, DIM);
  vec_gemm_relu<<<1, 256, 0, stream>>>(virt, W1, b1, h_v);
  gemm_nt_relu<<<gblk, 256, 0, stream>>>(h_s, W2, b2, e_s, M, DIM, DIM);
  gemm_nt_relu<<<gblk, 256, 0, stream>>>(h_t, W2, b2, e_t, M, DIM, DIM);
  vec_gemm_relu<<<1, 256, 0, stream>>>(h_v, W2, b2, e_v);

  cdist_kernel<<<dim3(5, 5, BATCH), 256, 0, stream>>>(e_s, e_t, e_v, d_raw);
  batch_sum<<<BATCH, 256, 0, stream>>>(d_raw, sums);
  normalize_kernel<<<(BATCH * EDSZ + 255) / 256, 256, 0, stream>>>(d_raw, sums, edit);
  lsap_kernel<<<BATCH, 64, 0, stream>>>(edit, Aout, geds);
}

// Round 11
// 823.648 us; speedup vs baseline: 1.2515x; 1.0967x over previous
//
#include <hip/hip_runtime.h>

// ---------------------------------------------------------------------------
// Problem constants (B=16, N=128, FIN=D=512)
// ---------------------------------------------------------------------------
#define BATCH 16
#define NNODE 128
#define DIM 512
#define NP1 129              // N+1 (with virtual node)
#define EDSZ (NP1 * NP1)     // 16641 per batch
#define BIGF 3.0e38f         // sentinel (finite)

// ---------------------------------------------------------------------------
// Fused dual-input GEMM (NT): Y{0,1}[m][n] = relu(sum_k X{0,1}[m][k]*W[n][k]+b[n])
// blockIdx.z selects input/output pair. 64x64 tile, BK=32, 256 threads,
// 4x4 microtile. LDS is k-major, stride 68 (16B aligned) so the inner loop
// uses ds_read_b128 (2 reads per 16 FMA vs 8 scalar reads before).
// ---------------------------------------------------------------------------
__global__ __launch_bounds__(256) void gemm2_nt_relu(
    const float* __restrict__ X0, const float* __restrict__ X1,
    const float* __restrict__ W, const float* __restrict__ bias,
    float* __restrict__ Y0, float* __restrict__ Y1,
    int M, int N, int K) {
  const float* X = blockIdx.z ? X1 : X0;
  float* Y = blockIdx.z ? Y1 : Y0;
  __shared__ float sA[32][68];
  __shared__ float sB[32][68];
  const int tid = threadIdx.x;
  const int m0 = blockIdx.x * 64;
  const int n0 = blockIdx.y * 64;
  const int tm = tid / 16, tn = tid % 16;
  const int lr = tid >> 2;          // 0..63 (tile row)
  const int lk8 = (tid & 3) * 8;    // 0,8,16,24 (k offset, 8 wide)
  float acc[4][4] = {};
  for (int k0 = 0; k0 < K; k0 += 32) {
    const float* xa = X + (size_t)(m0 + lr) * K + k0 + lk8;
    const float* wb = W + (size_t)(n0 + lr) * K + k0 + lk8;
    float4 a0 = *(const float4*)(xa);
    float4 a1 = *(const float4*)(xa + 4);
    float4 b0 = *(const float4*)(wb);
    float4 b1 = *(const float4*)(wb + 4);
    sA[lk8 + 0][lr] = a0.x; sA[lk8 + 1][lr] = a0.y;
    sA[lk8 + 2][lr] = a0.z; sA[lk8 + 3][lr] = a0.w;
    sA[lk8 + 4][lr] = a1.x; sA[lk8 + 5][lr] = a1.y;
    sA[lk8 + 6][lr] = a1.z; sA[lk8 + 7][lr] = a1.w;
    sB[lk8 + 0][lr] = b0.x; sB[lk8 + 1][lr] = b0.y;
    sB[lk8 + 2][lr] = b0.z; sB[lk8 + 3][lr] = b0.w;
    sB[lk8 + 4][lr] = b1.x; sB[lk8 + 5][lr] = b1.y;
    sB[lk8 + 6][lr] = b1.z; sB[lk8 + 7][lr] = b1.w;
    __syncthreads();
#pragma unroll
    for (int k = 0; k < 32; ++k) {
      const float4 a = *(const float4*)&sA[k][tm * 4];
      const float4 b = *(const float4*)&sB[k][tn * 4];
      acc[0][0] = fmaf(a.x, b.x, acc[0][0]);
      acc[0][1] = fmaf(a.x, b.y, acc[0][1]);
      acc[0][2] = fmaf(a.x, b.z, acc[0][2]);
      acc[0][3] = fmaf(a.x, b.w, acc[0][3]);
      acc[1][0] = fmaf(a.y, b.x, acc[1][0]);
      acc[1][1] = fmaf(a.y, b.y, acc[1][1]);
      acc[1][2] = fmaf(a.y, b.z, acc[1][2]);
      acc[1][3] = fmaf(a.y, b.w, acc[1][3]);
      acc[2][0] = fmaf(a.z, b.x, acc[2][0]);
      acc[2][1] = fmaf(a.z, b.y, acc[2][1]);
      acc[2][2] = fmaf(a.z, b.z, acc[2][2]);
      acc[2][3] = fmaf(a.z, b.w, acc[2][3]);
      acc[3][0] = fmaf(a.w, b.x, acc[3][0]);
      acc[3][1] = fmaf(a.w, b.y, acc[3][1]);
      acc[3][2] = fmaf(a.w, b.z, acc[3][2]);
      acc[3][3] = fmaf(a.w, b.w, acc[3][3]);
    }
    __syncthreads();
  }
#pragma unroll
  for (int i = 0; i < 4; ++i) {
    int m = m0 + tm * 4 + i;
#pragma unroll
    for (int j = 0; j < 4; ++j) {
      int n = n0 + tn * 4 + j;
      Y[(size_t)m * N + n] = fmaxf(acc[i][j] + bias[n], 0.f);
    }
  }
}

// ---------------------------------------------------------------------------
// Virtual-node embed, both layers in ONE block (LDS hand-off).
// ---------------------------------------------------------------------------
__global__ __launch_bounds__(256) void virt_embed(
    const float* __restrict__ x,
    const float* __restrict__ W1, const float* __restrict__ b1,
    const float* __restrict__ W2, const float* __restrict__ b2,
    float* __restrict__ e_v) {
  __shared__ float sx[DIM];
  __shared__ float sh[DIM];
  for (int k = threadIdx.x; k < DIM; k += 256) sx[k] = x[k];
  __syncthreads();
  for (int n = threadIdx.x; n < DIM; n += 256) {
    const float* w = W1 + (size_t)n * DIM;
    float s = 0.f;
    for (int k = 0; k < DIM; k += 4) {
      float4 wv = *(const float4*)(w + k);
      s = fmaf(sx[k + 0], wv.x, s);
      s = fmaf(sx[k + 1], wv.y, s);
      s = fmaf(sx[k + 2], wv.z, s);
      s = fmaf(sx[k + 3], wv.w, s);
    }
    sh[n] = fmaxf(s + b1[n], 0.f);
  }
  __syncthreads();
  for (int n = threadIdx.x; n < DIM; n += 256) {
    const float* w = W2 + (size_t)n * DIM;
    float s = 0.f;
    for (int k = 0; k < DIM; k += 4) {
      float4 wv = *(const float4*)(w + k);
      s = fmaf(sh[k + 0], wv.x, s);
      s = fmaf(sh[k + 1], wv.y, s);
      s = fmaf(sh[k + 2], wv.z, s);
      s = fmaf(sh[k + 3], wv.w, s);
    }
    e_v[n] = fmaxf(s + b2[n], 0.f);
  }
}

// ---------------------------------------------------------------------------
// cdist: d[b][i][j] = || esrow(b,i) - etrow(b,j) ||_2
// ---------------------------------------------------------------------------
__global__ __launch_bounds__(256) void cdist_kernel(
    const float* __restrict__ es, const float* __restrict__ et,
    const float* __restrict__ ev, float* __restrict__ d) {
  const int b = blockIdx.z;
  const int i0 = blockIdx.x * 32;
  const int j0 = blockIdx.y * 32;
  __shared__ float sA[32][33];
  __shared__ float sB[32][33];
  const int tid = threadIdx.x;
  const int ty = tid / 16, tx = tid % 16;
  const int lr = tid / 8;
  const int lk4 = (tid % 8) * 4;
  const int gi = i0 + lr;
  const int gj = j0 + lr;
  const float* pa = (gi < NNODE) ? (es + ((size_t)b * NNODE + gi) * DIM) : ev;
  const float* pb = (gj < NNODE) ? (et + ((size_t)b * NNODE + gj) * DIM) : ev;
  float acc[2][2] = {};
  for (int k0 = 0; k0 < DIM; k0 += 32) {
    float4 av = *(const float4*)(pa + k0 + lk4);
    float4 bv = *(const float4*)(pb + k0 + lk4);
    sA[lr][lk4 + 0] = av.x; sA[lr][lk4 + 1] = av.y;
    sA[lr][lk4 + 2] = av.z; sA[lr][lk4 + 3] = av.w;
    sB[lr][lk4 + 0] = bv.x; sB[lr][lk4 + 1] = bv.y;
    sB[lr][lk4 + 2] = bv.z; sB[lr][lk4 + 3] = bv.w;
    __syncthreads();
#pragma unroll 8
    for (int k = 0; k < 32; ++k) {
      float a0 = sA[ty * 2 + 0][k], a1 = sA[ty * 2 + 1][k];
      float b0 = sB[tx * 2 + 0][k], b1 = sB[tx * 2 + 1][k];
      float d00 = a0 - b0, d01 = a0 - b1, d10 = a1 - b0, d11 = a1 - b1;
      acc[0][0] = fmaf(d00, d00, acc[0][0]);
      acc[0][1] = fmaf(d01, d01, acc[0][1]);
      acc[1][0] = fmaf(d10, d10, acc[1][0]);
      acc[1][1] = fmaf(d11, d11, acc[1][1]);
    }
    __syncthreads();
  }
#pragma unroll
  for (int i = 0; i < 2; ++i) {
    int gi2 = i0 + ty * 2 + i;
#pragma unroll
    for (int j = 0; j < 2; ++j) {
      int gj2 = j0 + tx * 2 + j;
      if (gi2 < NP1 && gj2 < NP1)
        d[(size_t)b * EDSZ + gi2 * NP1 + gj2] = sqrtf(acc[i][j]);
    }
  }
}

// ---------------------------------------------------------------------------
// Deterministic per-batch sum (fp64 tree)
// ---------------------------------------------------------------------------
__global__ __launch_bounds__(256) void batch_sum(
    const float* __restrict__ d, float* __restrict__ sums) {
  const int b = blockIdx.x;
  double s = 0.0;
  for (int idx = threadIdx.x; idx < EDSZ; idx += 256)
    s += (double)d[(size_t)b * EDSZ + idx];
  __shared__ double red[256];
  red[threadIdx.x] = s;
  __syncthreads();
  for (int off = 128; off; off >>= 1) {
    if (threadIdx.x < off) red[threadIdx.x] += red[threadIdx.x + off];
    __syncthreads();
  }
  if (threadIdx.x == 0) sums[b] = (float)red[0];
}

// ---------------------------------------------------------------------------
// normalize: edit = d / sum[b] * N*N
// ---------------------------------------------------------------------------
__global__ __launch_bounds__(256) void normalize_kernel(
    const float* __restrict__ d, const float* __restrict__ sums,
    float* __restrict__ edit) {
  int idx = blockIdx.x * 256 + threadIdx.x;
  if (idx < BATCH * EDSZ) {
    int b = idx / EDSZ;
    edit[idx] = d[idx] / sums[b] * (float)(NNODE * NNODE);
  }
}

// ---------------------------------------------------------------------------
// cross-lane helpers: 32-bit packed argmin on the VALU pipe.
// key = (f32 bits of nonneg value with low 7 mantissa bits replaced by col).
// Unsigned order == value order (to within 2^-17 rel; ties -> lowest col).
// Exact values recovered by readlane from the winner lane, so dual
// arithmetic stays exact (perturbation limited to pop order, ~1e-6 abs —
// far inside the validated 8e-3 robustness margin).
// ---------------------------------------------------------------------------
__device__ __forceinline__ unsigned key_of(float m, int col) {
  return (__float_as_uint(m) & 0xFFFFFF80u) | (unsigned)col;
}

template <int CTRL>
__device__ __forceinline__ unsigned dpp_umin_step(unsigned x) {
  const unsigned o = (unsigned)__builtin_amdgcn_update_dpp(
      (int)0xFFFFFFFFu, (int)x, CTRL, 0xf, 0xf, false);
  return o < x ? o : x;
}

// wave64 min-key; result broadcast (readlane 63).
__device__ __forceinline__ unsigned wave_umin_key(unsigned x) {
  x = dpp_umin_step<0x111>(x);  // row_shr:1
  x = dpp_umin_step<0x112>(x);  // row_shr:2
  x = dpp_umin_step<0x114>(x);  // row_shr:4
  x = dpp_umin_step<0x118>(x);  // row_shr:8
  x = dpp_umin_step<0x142>(x);  // row_bcast:15
  x = dpp_umin_step<0x143>(x);  // row_bcast:31
  return (unsigned)__builtin_amdgcn_readlane((int)x, 63);
}

// merged (min1,min2) reduction: one DPP chain carries a sorted pair.
template <int CTRL>
__device__ __forceinline__ void dpp_umin2_step(unsigned& m1, unsigned& m2) {
  const unsigned o1 = (unsigned)__builtin_amdgcn_update_dpp(
      (int)0xFFFFFFFFu, (int)m1, CTRL, 0xf, 0xf, false);
  const unsigned o2 = (unsigned)__builtin_amdgcn_update_dpp(
      (int)0xFFFFFFFFu, (int)m2, CTRL, 0xf, 0xf, false);
  const unsigned lo = m1 < o1 ? m1 : o1;
  const unsigned hi = m1 < o1 ? o1 : m1;
  const unsigned yo = m2 < o2 ? m2 : o2;
  m1 = lo;
  m2 = hi < yo ? hi : yo;
}

__device__ __forceinline__ void wave_umin2_key(unsigned a, unsigned b,
                                               unsigned& k1, unsigned& k2) {
  unsigned m1 = a < b ? a : b;
  unsigned m2 = a < b ? b : a;
  dpp_umin2_step<0x111>(m1, m2);
  dpp_umin2_step<0x112>(m1, m2);
  dpp_umin2_step<0x114>(m1, m2);
  dpp_umin2_step<0x118>(m1, m2);
  dpp_umin2_step<0x142>(m1, m2);
  dpp_umin2_step<0x143>(m1, m2);
  k1 = (unsigned)__builtin_amdgcn_readlane((int)m1, 63);
  k2 = (unsigned)__builtin_amdgcn_readlane((int)m2, 63);
}

__device__ __forceinline__ float fsel2(float a0, float a1, int s) {
  return (s == 0) ? a0 : a1;
}
__device__ __forceinline__ int isel2(int a0, int a1, int s) {
  return (s == 0) ? a0 : a1;
}
__device__ __forceinline__ float readlane_f32(float x, int lane) {
  return __uint_as_float(
      (unsigned)__builtin_amdgcn_readlane((int)__float_as_uint(x), lane));
}

// ---------------------------------------------------------------------------
// LSAPE collapsed to a dense 128x128 LSAP, full LAPJV pipeline (R10 kernel,
// unchanged — validated best at ~572 us):
//   Phase 1 : column reduction; Phase 1r: reduction transfer;
//   Phase 1.5: budget-capped augmenting row reduction; Phase 2: exact SAP.
// ONE WAVE per batch, lane owns 2 columns, VALU-pipe cross-lane ops only.
// ---------------------------------------------------------------------------
__global__ __launch_bounds__(64) void lsap_kernel(
    const float* __restrict__ edit, float* __restrict__ Aout,
    float* __restrict__ geds) {
  const int b = blockIdx.x;
  const float* ec = edit + (size_t)b * EDSZ;
  float* A = Aout + (size_t)b * EDSZ;
  const int lane = threadIdx.x;
  const int cbase = lane * 2;  // first owned column (0-based), 2 per lane

  __shared__ float D[NNODE * NNODE];  // 64 KB dense collapsed cost

  // stage D = min(sub, del+ins); coalesced global reads (L2-resident)
  for (int idx = lane; idx < NNODE * NNODE; idx += 64) {
    const int i = idx >> 7, j = idx & 127;
    const float sub = ec[i * NP1 + j];
    const float di = ec[i * NP1 + NNODE] + ec[NNODE * NP1 + j];
    D[idx] = fminf(sub, di);
  }
  for (int idx = lane; idx < EDSZ; idx += 64) A[idx] = 0.f;
  __syncthreads();

  // per-lane state: 2 columns (v, minv, way, p) + 2 rows (u, x=row->col+1)
  float u0 = 0.f, u1 = 0.f;
  float v0 = 0.f, v1 = 0.f;
  float m0, m1;
  int w0 = 0, w1 = 0;
  int p0 = 0, p1 = 0;
  int x0 = 0, x1 = 0;

  // ---------------- Phase 1: column reduction on dense D ----------------
  int y0 = 0, y1 = 0;
  {
    float c0 = BIGF, c1 = BIGF;
    for (int r = 0; r < NNODE; ++r) {
      const float2 f = *(const float2*)&D[r * NNODE + cbase];
      if (f.x < c0) { c0 = f.x; y0 = r; }
      if (f.y < c1) { c1 = f.y; y1 = r; }
    }
    v0 = c0; v1 = c1;
  }

  // Greedy conflict-free assignment (wave-uniform scalar walk over columns).
  unsigned long long ra0 = 0, ra1 = 0;  // assigned-row bits (0..63, 64..127)
  for (int j = 0; j < NNODE; ++j) {
    const int jl = j >> 1, jq = j & 1;
    const int i1 = __builtin_amdgcn_readlane(isel2(y0, y1, jq), jl);
    const int bit = i1 & 63;
    const unsigned long long msk = (i1 < 64) ? ra0 : ra1;
    if (!((msk >> bit) & 1ull)) {
      if (i1 < 64) ra0 |= 1ull << bit; else ra1 |= 1ull << bit;
      if (lane == jl) {
        if (jq == 0) p0 = i1 + 1;
        else p1 = i1 + 1;
      }
      if (lane == (i1 >> 1)) {
        if ((i1 & 1) == 0) x0 = j + 1;
        else x1 = j + 1;
      }
    }
  }

  // ---------------- Phase 1r: reduction transfer ----------------
  for (int ii = 0; ii < NNODE; ++ii) {
    const int xj = __builtin_amdgcn_readlane(isel2(x0, x1, ii & 1), ii >> 1);
    if (xj == 0) continue;
    const int j1 = xj - 1;
    const float2 f = *(const float2*)&D[ii * NNODE + cbase];
    float r0 = fmaxf(f.x - v0, 0.f);
    float r1 = fmaxf(f.y - v1, 0.f);
    if (cbase + 0 == j1) r0 = BIGF;
    if (cbase + 1 == j1) r1 = BIGF;
    const unsigned ka = key_of(r0, cbase + 0);
    const unsigned kb = key_of(r1, cbase + 1);
    const unsigned kmin = wave_umin_key(ka < kb ? ka : kb);
    const int jm = (int)(kmin & 127u);
    const float umin = readlane_f32(fsel2(r0, r1, jm & 1), jm >> 1);
    if (lane == (j1 >> 1)) {
      if ((j1 & 1) == 0) v0 -= umin; else v1 -= umin;
    }
    if (lane == (ii >> 1)) {
      if ((ii & 1) == 0) u0 = umin; else u1 = umin;
    }
  }

  // ---------------- Phase 1.5: augmenting row reduction (budget-capped) ----
  {
    const int nfree0 =
        NNODE - __builtin_popcountll(ra0) - __builtin_popcountll(ra1);
    const int budget = 2 * nfree0 + 8;
    for (int step = 0; step < budget; ++step) {
      const unsigned long long fm0 = ~ra0, fm1 = ~ra1;
      int i;
      if (fm0) i = __builtin_ctzll(fm0);
      else if (fm1) i = 64 + __builtin_ctzll(fm1);
      else break;

      const float2 f = *(const float2*)&D[i * NNODE + cbase];
      const float r0 = fmaxf(f.x - v0, 0.f);
      const float r1 = fmaxf(f.y - v1, 0.f);
      unsigned k1, k2;
      wave_umin2_key(key_of(r0, cbase + 0), key_of(r1, cbase + 1), k1, k2);
      const int j1 = (int)(k1 & 127u), j2 = (int)(k2 & 127u);
      const float u1v = readlane_f32(fsel2(r0, r1, j1 & 1), j1 >> 1);
      const float u2v = readlane_f32(fsel2(r0, r1, j2 & 1), j2 >> 1);

      int jt = j1;
      int i1 = __builtin_amdgcn_readlane(isel2(p0, p1, j1 & 1), j1 >> 1);
      if (u1v < u2v) {
        const float dv = u2v - u1v;
        if (lane == (j1 >> 1)) {
          if ((j1 & 1) == 0) v0 -= dv; else v1 -= dv;
        }
      } else if (i1 != 0) {
        jt = j2;
        i1 = __builtin_amdgcn_readlane(isel2(p0, p1, j2 & 1), j2 >> 1);
      }
      // assign i -> jt with exact u[i] = u2v (feasible + tight)
      if (lane == (jt >> 1)) {
        if ((jt & 1) == 0) p0 = i + 1; else p1 = i + 1;
      }
      if (lane == (i >> 1)) {
        if ((i & 1) == 0) u0 = u2v; else u1 = u2v;
      }
      if (i < 64) ra0 |= 1ull << i; else ra1 |= 1ull << (i - 64);
      if (i1 != 0) {
        const int rr = i1 - 1;
        if (rr < 64) ra0 &= ~(1ull << rr); else ra1 &= ~(1ull << (rr - 64));
        if (lane == (rr >> 1)) {  // freed row: reset dual (always feasible)
          if ((rr & 1) == 0) u0 = 0.f; else u1 = 0.f;
        }
      }
    }
  }

  // ---------------- Phase 2: SAP for each remaining free row ----------------
  for (int ii = 0; ii < NNODE; ++ii) {
    const unsigned long long amsk = (ii < 64) ? ra0 : ra1;
    if ((amsk >> (ii & 63)) & 1ull) continue;  // assigned in phase 1/1.5
    const int i = ii + 1;

    unsigned cused = 0, rused = 0;
    m0 = m1 = BIGF;
    int j0 = 0;       // current column (0 = dummy start)
    int i0 = i;       // p[0] = i
    for (int guard = 0; guard <= NNODE; ++guard) {
      // --- mark used: column j0 (skip dummy col 0) and its row i0 ---
      if (j0 > 0 && lane == ((j0 - 1) >> 1)) {
        if (((j0 - 1) & 1) == 0) { cused |= 1u; m0 = BIGF; }
        else { cused |= 2u; m1 = BIGF; }
      }
      if (lane == ((i0 - 1) >> 1)) rused |= 1u << ((i0 - 1) & 1);

      // --- broadcast u[i0] from owning lane (i0 uniform -> readlane) ---
      const float u_i0 = readlane_f32(fsel2(u0, u1, (i0 - 1) & 1), (i0 - 1) >> 1);

      // --- dense cost row: one float2 per lane ---
      const float2 f = *(const float2*)&D[(i0 - 1) * NNODE + cbase];

      // --- relax free columns; clamp >=0 keeps key ordering sound ---
      const bool f0 = !(cused & 1u), f1 = !(cused & 2u);
      {
        float cur = fmaxf(f.x - u_i0 - v0, 0.f);
        bool up = f0 && (cur < m0);
        m0 = up ? cur : m0; w0 = up ? j0 : w0;
      }
      {
        float cur = fmaxf(f.y - u_i0 - v1, 0.f);
        bool up = f1 && (cur < m1);
        m1 = up ? cur : m1; w1 = up ? j0 : w1;
      }

      // --- 32-bit key argmin; exact delta via winner readlane ---
      const unsigned ka = key_of(m0, cbase + 0);
      const unsigned kb = key_of(m1, cbase + 1);
      const unsigned kmin = wave_umin_key(ka < kb ? ka : kb);
      const int jcol = (int)(kmin & 127u);
      const float delta = readlane_f32(fsel2(m0, m1, jcol & 1), jcol >> 1);
      const int j1 = jcol + 1;

      // --- dual updates (registers only) ---
      if (!f0) v0 -= delta; else m0 = fmaxf(m0 - delta, 0.f);
      if (!f1) v1 -= delta; else m1 = fmaxf(m1 - delta, 0.f);
      if (rused & 1u) u0 += delta;
      if (rused & 2u) u1 += delta;

      // --- next (or break on free column) ---
      const int pj1 = __builtin_amdgcn_readlane(
          isel2(p0, p1, (j1 - 1) & 1), (j1 - 1) >> 1);
      j0 = j1;
      if (pj1 == 0) break;
      i0 = pj1;
    }

    // --- augment along way[] chain (uniform walk via readlane) ---
    int jc = j0;
    while (jc != 0) {
      const int cl = (jc - 1) >> 1, cq = (jc - 1) & 1;
      const int jp = __builtin_amdgcn_readlane(isel2(w0, w1, cq), cl);
      const int js = (jp == 0) ? 1 : jp;  // safe index for speculative readlane
      const int pvr = __builtin_amdgcn_readlane(
          isel2(p0, p1, (js - 1) & 1), (js - 1) >> 1);
      const int pv = (jp == 0) ? i : pvr;
      if (lane == cl) {
        if (cq == 0) p0 = pv;
        else p1 = pv;
      }
      jc = jp;
    }
  }

  // --- emit A and geds: column j assigned row p[j+1]-1; re-split branches ---
  double contrib = 0.0;
  {
    const int pr[2] = {p0, p1};
#pragma unroll
    for (int q = 0; q < 2; ++q) {
      const int j = cbase + q;
      const int i = pr[q] - 1;
      const float sub = ec[i * NP1 + j];
      const float di = ec[i * NP1 + NNODE] + ec[NNODE * NP1 + j];
      if (sub < di) {
        A[i * NP1 + j] = 1.f;
        contrib += (double)sub;
      } else {
        A[i * NP1 + NNODE] = 1.f;    // delete row i
        A[NNODE * NP1 + j] = 1.f;    // insert col j
        contrib += (double)di;
      }
    }
  }
#pragma unroll
  for (int off = 32; off; off >>= 1) contrib += __shfl_xor(contrib, off);
  if (lane == 0) geds[b] = (float)(contrib / 256.0);
}

// ---------------------------------------------------------------------------
// launch
// ---------------------------------------------------------------------------
extern "C" void kernel_launch(void* const* d_in, const int* in_sizes, int n_in,
                              void* d_out, int out_size, void* d_ws, size_t ws_size,
                              hipStream_t stream) {
  const float* x_s  = (const float*)d_in[0];
  const float* x_t  = (const float*)d_in[1];
  const float* W1   = (const float*)d_in[2];
  const float* b1   = (const float*)d_in[3];
  const float* W2   = (const float*)d_in[4];
  const float* b2   = (const float*)d_in[5];
  const float* virt = (const float*)d_in[6];

  const int M = BATCH * NNODE;  // 2048

  float* ws    = (float*)d_ws;
  float* h_s   = ws;
  float* h_t   = h_s + (size_t)M * DIM;
  float* e_s   = h_t + (size_t)M * DIM;
  float* e_t   = e_s + (size_t)M * DIM;
  float* e_v   = e_t + (size_t)M * DIM;      // 512
  float* d_raw = e_v + DIM;
  float* sums  = d_raw + (size_t)BATCH * EDSZ;

  float* Aout = (float*)d_out;
  float* edit = Aout + (size_t)BATCH * EDSZ;
  float* geds = edit + (size_t)BATCH * EDSZ;

  dim3 gblk(M / 64, DIM / 64, 2);  // (32, 8, 2)
  virt_embed<<<1, 256, 0, stream>>>(virt, W1, b1, W2, b2, e_v);
  gemm2_nt_relu<<<gblk, 256, 0, stream>>>(x_s, x_t, W1, b1, h_s, h_t, M, DIM, DIM);
  gemm2_nt_relu<<<gblk, 256, 0, stream>>>(h_s, h_t, W2, b2, e_s, e_t, M, DIM, DIM);

  cdist_kernel<<<dim3(5, 5, BATCH), 256, 0, stream>>>(e_s, e_t, e_v, d_raw);
  batch_sum<<<BATCH, 256, 0, stream>>>(d_raw, sums);
  normalize_kernel<<<(BATCH * EDSZ + 255) / 256, 256, 0, stream>>>(d_raw, sums, edit);
  lsap_kernel<<<BATCH, 64, 0, stream>>>(edit, Aout, geds);
}